// Round 4
// baseline (208.812 us; speedup 1.0000x reference)
//
#include <hip/hip_runtime.h>
#include <hip/hip_bf16.h>

typedef __bf16 bf16;
typedef __bf16 bf16x8 __attribute__((ext_vector_type(8)));
typedef float f32x4 __attribute__((ext_vector_type(4)));

#define BB 64
#define EMB 256
#define UNITS 512
#define POI 5000
#define KCAT 1280
#define SCLD 5024   // sc row stride (5000 padded to x32)
#define L2E 1.4426950408889634f

__device__ __forceinline__ float rcp_(float x){ return __builtin_amdgcn_rcpf(x); }
__device__ __forceinline__ float exp2_(float x){ return __builtin_amdgcn_exp2f(x); }

__device__ __forceinline__ bf16x8 cvt8(f32x4 a0, f32x4 a1){
  bf16x8 o;
#pragma unroll
  for(int j=0;j<4;j++){ o[j]=(bf16)a0[j]; o[4+j]=(bf16)a1[j]; }
  return o;
}

// ---- fp32-A x fp32-B(strided) MFMA tile helper (k_logits; B cacheline-shared scalars).
__device__ __forceinline__ f32x4 mm16r(const float* __restrict__ ap, const float* __restrict__ B,
                                       int ldb, int K, int nc, int lane){
  int q = lane >> 4;
  f32x4 acc = {0.f,0.f,0.f,0.f};
  ap += q*8;
  const float* bp = B + (size_t)(q*8)*ldb + nc;
#pragma unroll 2
  for(int k0 = 0; k0 < K; k0 += 32){
    bf16x8 a = cvt8(*(const f32x4*)ap, *(const f32x4*)(ap+4));
    bf16x8 b;
#pragma unroll
    for(int j=0;j<8;j++) b[j] = (bf16)bp[(size_t)j*ldb];
    acc = __builtin_amdgcn_mfma_f32_16x16x32_bf16(a, b, acc, 0, 0, 0);
    ap += 32; bp += (size_t)32*ldb;
  }
  return acc;
}
__device__ __forceinline__ f32x4 mm16f(const float* __restrict__ A, const float* __restrict__ B,
                                       int lda, int ldb, int K, int mr, int nc, int lane){
  return mm16r(A + (size_t)mr*lda, B, ldb, K, nc, lane);
}

// ---- 64-row transpose tile: src fp32 [nRv][srcLd] rows [r0,r0+64) cols [c0,c0+cW)
//      -> dstT bf16 (dstT[c][r] = src[r][c]); src rows >= nRv produce 0 (pad fill).
__device__ __forceinline__ void t64(const float* __restrict__ src, int srcLd, int nRv,
    int r0, int c0, int cW, bf16* __restrict__ dstT, int dstLd, int dstRmax,
    int lane, int w){
  int r = r0 + lane;
  bool rv = r < nRv;
  int cw4 = cW >> 2;
  int cb = c0 + w*cw4;
  for(int c8=0;c8<cw4;c8+=8){
    int c = cb + c8;
    f32x4 v0={0.f,0.f,0.f,0.f}, v1={0.f,0.f,0.f,0.f};
    if(rv){ v0 = *(const f32x4*)(src + (size_t)r*srcLd + c);
            v1 = *(const f32x4*)(src + (size_t)r*srcLd + c + 4); }
    if(r < dstRmax){
#pragma unroll
      for(int j=0;j<4;j++){
        dstT[(size_t)(c+j)*dstLd + r]   = (bf16)v0[j];
        dstT[(size_t)(c+4+j)*dstLd + r] = (bf16)v1[j];
      }
    }
  }
}

// ---- prep: bf16 packs/transposes, out=bias broadcast, outc zero+catd, sumb init. grid 465.
__global__ __launch_bounds__(256) void k_prep0(
    const float* __restrict__ emb, const float* __restrict__ W1, const float* __restrict__ W2,
    const float* __restrict__ gruK, const float* __restrict__ gruR,
    const float* __restrict__ fcb, const float* __restrict__ catd,
    float* __restrict__ out, float* __restrict__ outc,
    bf16* __restrict__ embB, bf16* __restrict__ embTb,
    bf16* __restrict__ W1Tb, bf16* __restrict__ W2Tb,
    bf16* __restrict__ gruKTb, bf16* __restrict__ gruRTb,
    float* __restrict__ sumb){
  int bx = blockIdx.x, t = threadIdx.x, lane = t & 63, w = t >> 6;
  if(bx < 80){                       // embB: rows [bx*64,+64), coalesced fp32->bf16
    int r0 = bx*64;
    for(int ch = t; ch < 2048; ch += 256){
      int r = r0 + (ch >> 5), cc = (ch & 31)*8;
      if(r < POI){
        f32x4 v0 = *(const f32x4*)(emb + (size_t)r*EMB + cc);
        f32x4 v1 = *(const f32x4*)(emb + (size_t)r*EMB + cc + 4);
        *(bf16x8*)(embB + (size_t)r*EMB + cc) = cvt8(v0, v1);
      }
    }
  } else if(bx < 240){               // embTb [256][5024]
    int i = bx - 80;
    t64(emb, EMB, POI, (i>>1)*64, (i&1)*128, 128, embTb, SCLD, SCLD, lane, w);
  } else if(bx < 256){               // W2Tb [512][512]
    int i = bx - 240;
    t64(W2, UNITS, UNITS, (i>>1)*64, (i&1)*256, 256, W2Tb, UNITS, UNITS, lane, w);
  } else if(bx < 264){               // W1Tb [512][256]
    int i = bx - 256;
    t64(W1, UNITS, EMB, (i>>1)*64, (i&1)*256, 256, W1Tb, EMB, EMB, lane, w);
  } else if(bx < 328){               // gruKTb [1536][512]
    int i = bx - 264;
    t64(gruK, 1536, 512, (i>>3)*64, (i&7)*192, 192, gruKTb, 512, 512, lane, w);
  } else if(bx < 392){               // gruRTb [1536][512]
    int i = bx - 328;
    t64(gruR, 1536, 512, (i>>3)*64, (i&7)*192, 192, gruRTb, 512, 512, lane, w);
  } else if(bx < 456){               // out row (bx-392): init with fc bias (folds k_logits bias)
    int b = bx - 392;
    for(int n=t; n<POI; n+=256) out[(size_t)b*POI + n] = fcb[n];
  } else if(bx < 464){               // outc: zero ctx region + catd copy, 8 rows/block
    int base = (bx - 456)*8;
    for(int i=t; i<8*768; i+=256){
      int bb = base + i/768, c = i - (i/768)*768;
      if(c < 256) outc[(size_t)bb*KCAT + c] = 0.f;
      else        outc[(size_t)bb*KCAT + 512 + c] = catd[(size_t)bb*512 + (c-256)];
    }
  } else {                           // sumb init
    if(t < BB) sumb[t] = 0.f;
  }
}

// ---- fused GRU: both GEMMs (full K=512) + gate math in one kernel.
// grid 64 = (32 u-tiles) x (2 b-halves), 384 thr = 6 waves: {xm,hm} x {z,r,h}.
__global__ __launch_bounds__(384) void k_gruga(const int* __restrict__ x, const float* __restrict__ query,
    const bf16* __restrict__ embB, const float* __restrict__ h0,
    const bf16* __restrict__ gruKTb, const bf16* __restrict__ gruRTb,
    const float* __restrict__ bias,
    float* __restrict__ hn, float* __restrict__ outc, float* __restrict__ dout){
  __shared__ float tiles[6][32][17];
  int t = threadIdx.x, lane = t & 63, w = t >> 6;      // w 0..5
  int b0 = (blockIdx.x & 1)*32;
  int u0 = (blockIdx.x >> 1)*16;
  int y = w/3, g = w - y*3;                             // y: 0=xm 1=hm; g: gate z/r/h
  int q = lane >> 4;
  int col = g*512 + u0 + (lane & 15);
  const bf16* KT = (y ? gruRTb : gruKTb) + (size_t)col*512 + q*8;
#pragma unroll
  for(int pq=0;pq<2;pq++){
    int mr = b0 + pq*16 + (lane & 15);
    f32x4 acc = {0.f,0.f,0.f,0.f};
    const bf16* bp = KT;
    if(y){
      const float* apf = h0 + (size_t)mr*512 + q*8;
#pragma unroll
      for(int k0=0;k0<512;k0+=32){
        bf16x8 a = cvt8(*(const f32x4*)apf, *(const f32x4*)(apf+4));
        acc = __builtin_amdgcn_mfma_f32_16x16x32_bf16(a, *(const bf16x8*)bp, acc, 0,0,0);
        apf += 32; bp += 32;
      }
    } else {
      const bf16* ap = embB + (size_t)x[mr]*EMB + q*8;
#pragma unroll
      for(int k0=0;k0<256;k0+=32){
        acc = __builtin_amdgcn_mfma_f32_16x16x32_bf16(*(const bf16x8*)ap, *(const bf16x8*)bp, acc, 0,0,0);
        ap += 32; bp += 32;
      }
      const float* apf = query + (size_t)mr*256 + q*8;
#pragma unroll
      for(int k0=0;k0<256;k0+=32){
        bf16x8 a = cvt8(*(const f32x4*)apf, *(const f32x4*)(apf+4));
        acc = __builtin_amdgcn_mfma_f32_16x16x32_bf16(a, *(const bf16x8*)bp, acc, 0,0,0);
        apf += 32; bp += 32;
      }
    }
#pragma unroll
    for(int r=0;r<4;r++) tiles[w][pq*16 + q*4 + r][lane & 15] = acc[r];
  }
  __syncthreads();
  for(int i=t;i<512;i+=384){
    int bl = i >> 4, j = i & 15;
    int b = b0 + bl, u = u0 + j;
    float xz = tiles[0][bl][j] + bias[u];
    float xr = tiles[1][bl][j] + bias[512+u];
    float xh = tiles[2][bl][j] + bias[1024+u];
    float hz = tiles[3][bl][j] + bias[1536+u];
    float hr = tiles[4][bl][j] + bias[2048+u];
    float hh = tiles[5][bl][j] + bias[2560+u];
    float z = rcp_(1.f + exp2_(-L2E*(xz+hz)));
    float r = rcp_(1.f + exp2_(-L2E*(xr+hr)));
    float ca = xh + r*hh;
    ca = fminf(fmaxf(ca, -15.f), 15.f);
    float e = exp2_(2.f*L2E*ca);
    float hc = (e - 1.f)*rcp_(e + 1.f);
    float h = h0[(size_t)b*512+u];
    float v = z*h + (1.f - z)*hc;
    hn[(size_t)b*512+u] = v;
    outc[(size_t)b*KCAT + 256 + u] = v;
    dout[(size_t)POI*BB + (size_t)b*512 + u] = v;                       // state
    dout[(size_t)POI*BB + (size_t)BB*512 + (size_t)b*512 + u] = v;      // output_
  }
}

// ---- Eq = exp2(clamp(2*log2e*(hn@W2 + b2))): grid 128 (4 r x 32 c), 4-way K-split, LDS reduce.
__global__ __launch_bounds__(256) void k_qproj(const float* __restrict__ hn, const bf16* __restrict__ W2Tb,
                        const float* __restrict__ W2b, float* __restrict__ Eq){
  __shared__ float accs[16][17];
  int t = threadIdx.x, lane = t & 63, w = t >> 6;
  int c16 = blockIdx.x & 31, r16 = blockIdx.x >> 5;
  for(int i=t;i<16*17;i+=256) ((float*)accs)[i] = 0.f;
  __syncthreads();
  int q = lane >> 4;
  int mr  = r16*16 + (lane & 15);
  int col = c16*16 + (lane & 15);
  const float* ap = hn + (size_t)mr*UNITS + w*128 + q*8;
  const bf16*  bp = W2Tb + (size_t)col*UNITS + w*128 + q*8;
  f32x4 acc = {0.f,0.f,0.f,0.f};
#pragma unroll
  for(int k0=0;k0<128;k0+=32){
    bf16x8 a = cvt8(*(const f32x4*)ap, *(const f32x4*)(ap+4));
    bf16x8 b = *(const bf16x8*)bp;
    acc = __builtin_amdgcn_mfma_f32_16x16x32_bf16(a,b,acc,0,0,0);
    ap += 32; bp += 32;
  }
#pragma unroll
  for(int r=0;r<4;r++) atomicAdd(&accs[q*4+r][lane & 15], acc[r]);
  __syncthreads();
  int r = t >> 4, c = t & 15;
  int colg = c16*16 + c;
  float v = (accs[r][c] + W2b[colg])*(2.f*L2E);
  Eq[(size_t)(r16*16+r)*UNITS + colg] = exp2_(fminf(fmaxf(v,-40.f),40.f));
}

// ---- fused vproj+score, grid (313, NY): 16 poi rows x (512/NY)-u slice per block.
template<int NY>
__global__ __launch_bounds__(256, 8) void k_vscore(
    const bf16* __restrict__ embB, const bf16* __restrict__ W1Tb,
    const float* __restrict__ W1b, const float* __restrict__ Eq,
    const float* __restrict__ Vw, float* __restrict__ scS){
  constexpr int USL = 512/NY;
  __shared__ float evsT[USL][20];      // [u_local][p_local(16) + pad]
  __shared__ float vws[USL];
  int t = threadIdx.x, lane = t & 63, w = t >> 6;
  int p0 = blockIdx.x*16, uh = blockIdx.y*USL;
  int q = lane >> 4;
  int mr = p0 + (lane & 15); if(mr > POI-1) mr = POI-1;
#pragma unroll
  for(int i=0;i<USL/64;i++){
    int colL = (w + 4*i)*16 + (lane & 15);
    const bf16* ap = embB + (size_t)mr*EMB + q*8;
    const bf16* bp = W1Tb + (size_t)(uh+colL)*EMB + q*8;
    f32x4 acc = {0.f,0.f,0.f,0.f};
#pragma unroll
    for(int k0=0;k0<EMB;k0+=32){
      bf16x8 a = *(const bf16x8*)ap, b = *(const bf16x8*)bp;
      acc = __builtin_amdgcn_mfma_f32_16x16x32_bf16(a,b,acc,0,0,0);
      ap += 32; bp += 32;
    }
    float bn = W1b[uh+colL];
    f32x4 ev;
#pragma unroll
    for(int r=0;r<4;r++){
      float v = (acc[r] + bn)*(2.f*L2E);
      ev[r] = exp2_(fminf(fmaxf(v,-40.f),40.f));
    }
    *(f32x4*)&evsT[colL][q*4] = ev;    // transposed: 4 consecutive p
  }
  if(t < USL) vws[t] = Vw[uh + t];
  __syncthreads();
  int pg = t & 3, b = t >> 2;
  const float* qrow = Eq + (size_t)b*UNITS + uh;
  f32x4 s = {0.f,0.f,0.f,0.f};
#pragma unroll 4
  for(int u4=0; u4<USL/4; ++u4){
    f32x4 q4 = *(const f32x4*)&qrow[u4*4];
    f32x4 wv = *(const f32x4*)&vws[u4*4];
#pragma unroll
    for(int j=0;j<4;j++){
      f32x4 ev = *(const f32x4*)&evsT[u4*4+j][4*pg];
#pragma unroll
      for(int e=0;e<4;e++)
        s[e] += wv[j]*rcp_(ev[e]*q4[j] + 1.f);
    }
  }
  int pA = p0 + 4*pg;
  float* srow = scS + (size_t)blockIdx.y*BB*SCLD + (size_t)b*SCLD + pA;
  if(pA + 3 < POI) *(f32x4*)srow = s;
  else {
#pragma unroll
    for(int e=0;e<4;e++) if(pA+e < POI) srow[e] = s[e];
  }
}

// ---- single-pass softmax numerator: e = exp(-2*sum_y sc_y) (bounded, no max-sub needed;
//      const SW shift cancels in normalization); atomicAdd per-b sum; zero k-pad. grid (64,8).
__global__ __launch_bounds__(256) void k_smax(float* __restrict__ sc, float* __restrict__ sumb,
                                              int nslab){
  __shared__ float red[256];
  int b = blockIdx.x, y = blockIdx.y, t = threadIdx.x;
  float* sA = sc + (size_t)b*SCLD;
  int pend = (y+1)*640; if(pend > POI) pend = POI;
  float sm = 0.f;
  for(int p = y*640 + t; p < pend; p += 256){
    float acc = sA[p];
    for(int s2=1;s2<nslab;s2++) acc += sA[(size_t)s2*BB*SCLD + p];
    float e = exp2_(-2.f*L2E*acc);
    sA[p] = e;                         // unnormalized; k_ctx applies 1/sum
    sm += e;
  }
  if(y == 7 && t < SCLD-POI) sA[POI + t] = 0.f;
  red[t] = sm; __syncthreads();
  for(int o=128;o>0;o>>=1){ if(t<o) red[t]+=red[t+o]; __syncthreads(); }
  if(t==0) atomicAdd(sumb + b, red[0]);
}

// ---- context = wb[64,5024] @ embTb (bf16, contiguous), split-K x79, scaled 1/sum
__global__ __launch_bounds__(256) void k_ctx(const float* __restrict__ wb, const bf16* __restrict__ embTb,
                                             const float* __restrict__ sumb, float* __restrict__ outc){
  int lane = threadIdx.x & 63, w = threadIdx.x >> 6;
  int n = blockIdx.x*16 + (lane & 15);       // n < 256
  int ky = blockIdx.y;                        // 79 splits of 64 (last 32)
  int kbeg = ky*64;
  int K = (ky == 78) ? 32 : 64;
  int mr = w*16 + (lane & 15);
  int q = lane >> 4;
  const float* ap = wb + (size_t)mr*SCLD + kbeg + q*8;
  const bf16*  bp = embTb + (size_t)n*SCLD + kbeg + q*8;
  f32x4 acc = {0.f,0.f,0.f,0.f};
  for(int k0=0;k0<K;k0+=32){
    bf16x8 a = cvt8(*(const f32x4*)ap, *(const f32x4*)(ap+4));
    bf16x8 b = *(const bf16x8*)bp;
    acc = __builtin_amdgcn_mfma_f32_16x16x32_bf16(a,b,acc,0,0,0);
    ap += 32; bp += 32;
  }
  int rb = w*16 + (lane >> 4)*4;
#pragma unroll
  for(int r=0;r<4;r++) atomicAdd(&outc[(size_t)(rb+r)*KCAT + n], acc[r]*rcp_(sumb[rb+r]));
}

// ---- logits: split-K x8, atomicAdd onto bias-preinitialized d_out. grid (313,8).
__global__ __launch_bounds__(256) void k_logits(const float* __restrict__ A, const float* __restrict__ Bw,
                        float* __restrict__ out){
  int lane = threadIdx.x & 63, w = threadIdx.x >> 6;
  int n = blockIdx.x*16 + (lane & 15);
  int nc = n < POI ? n : POI-1;
  int ky = blockIdx.y, kbeg = ky*160;         // 8 x 160 = 1280
  f32x4 acc = mm16f(A + kbeg, Bw + (size_t)kbeg*POI, KCAT, POI, 160,
                    w*16 + (lane & 15), nc, lane);
  int rb = w*16 + (lane >> 4)*4;
  if(n < POI){
#pragma unroll
    for(int r=0;r<4;r++) atomicAdd(&out[(size_t)(rb+r)*POI + n], acc[r]);
  }
}

extern "C" void kernel_launch(void* const* d_in, const int* in_sizes, int n_in,
                              void* d_out, int out_size, void* d_ws, size_t ws_size,
                              hipStream_t stream){
  const int*   x     = (const int*)d_in[0];
  const float* query = (const float*)d_in[1];
  const float* emb   = (const float*)d_in[2];
  // d_in[3] A_hat unused by reference
  const float* h0    = (const float*)d_in[4];
  const float* catd  = (const float*)d_in[5];
  const float* gruK  = (const float*)d_in[6];
  const float* gruR  = (const float*)d_in[7];
  const float* gruB  = (const float*)d_in[8];
  const float* W1    = (const float*)d_in[9];
  const float* W1b   = (const float*)d_in[10];
  const float* W2    = (const float*)d_in[11];
  const float* W2b   = (const float*)d_in[12];
  const float* Vw    = (const float*)d_in[13];
  // d_in[14] V_b: softmax-invariant, dropped
  const float* fcw   = (const float*)d_in[15];
  const float* fcb   = (const float*)d_in[16];
  float* out = (float*)d_out;

  int nslab = (ws_size >= (size_t)24*1024*1024) ? 8 : 4;

  char* ws = (char*)d_ws;
  size_t off = 0;
  auto alloc = [&](size_t bytes)->void*{ void* p = ws + off; off += (bytes + 255) & ~(size_t)255; return p; };
  float* outc   = (float*)alloc((size_t)BB*KCAT*4);
  float* hn     = (float*)alloc((size_t)BB*512*4);
  float* Eq     = (float*)alloc((size_t)BB*512*4);
  bf16*  embB   = (bf16*)alloc((size_t)POI*EMB*2);
  bf16*  embTb  = (bf16*)alloc((size_t)EMB*SCLD*2);
  bf16*  W1Tb   = (bf16*)alloc((size_t)UNITS*EMB*2);
  bf16*  W2Tb   = (bf16*)alloc((size_t)UNITS*UNITS*2);
  bf16*  gruKTb = (bf16*)alloc((size_t)1536*512*2);
  bf16*  gruRTb = (bf16*)alloc((size_t)1536*512*2);
  float* sumb   = (float*)alloc((size_t)BB*4);
  float* sc     = (float*)alloc((size_t)nslab*BB*SCLD*4);

  k_prep0  <<<465, 256, 0, stream>>>(emb, W1, W2, gruK, gruR, fcb, catd, out, outc,
                                     embB, embTb, W1Tb, W2Tb, gruKTb, gruRTb, sumb);
  k_gruga  <<<64, 384, 0, stream>>>(x, query, embB, h0, gruKTb, gruRTb, gruB, hn, outc, out);
  k_qproj  <<<128, 256, 0, stream>>>(hn, W2Tb, W2b, Eq);
  if(nslab == 8)
    k_vscore<8><<<dim3(313,8), 256, 0, stream>>>(embB, W1Tb, W1b, Eq, Vw, sc);
  else
    k_vscore<4><<<dim3(313,4), 256, 0, stream>>>(embB, W1Tb, W1b, Eq, Vw, sc);
  k_smax   <<<dim3(BB,8), 256, 0, stream>>>(sc, sumb, nslab);
  k_ctx    <<<dim3(16,79), 256, 0, stream>>>(sc, embTb, sumb, outc);
  k_logits <<<dim3(313,8), 256, 0, stream>>>(outc, fcw, out);
}